// Round 3
// baseline (70.023 us; speedup 1.0000x reference)
//
#include <hip/hip_runtime.h>

constexpr int FIELD = 26;
constexpr int EDIM  = 32;
constexpr int NPAIR = 325;   // C(26,2)
constexpr int BTB   = 256;   // batch rows per block (64 per wave)

typedef __bf16 bf16x8 __attribute__((ext_vector_type(8)));
typedef float  f32x4  __attribute__((ext_vector_type(4)));

static __device__ inline bf16x8 cvt8(const float4 a, const float4 b) {
    bf16x8 r;
    r[0] = (__bf16)a.x; r[1] = (__bf16)a.y; r[2] = (__bf16)a.z; r[3] = (__bf16)a.w;
    r[4] = (__bf16)b.x; r[5] = (__bf16)b.y; r[6] = (__bf16)b.z; r[7] = (__bf16)b.w;
    return r;
}

__global__ __launch_bounds__(256) void bilinear_mfma(
    const float* __restrict__ x,     // [B][26][32]
    const float* __restrict__ W,     // [325][32][32]  W[p][e][d]
    const float* __restrict__ bias,  // [325][32]
    float* __restrict__ out)         // [B][325][32]
{
    const int p  = blockIdx.x;
    const int b0 = blockIdx.y * BTB;

    // triu_indices(26, k=1) -> (fi, fj); wave-uniform.
    int fi = 0, rem = p;
    #pragma unroll 1
    while (rem >= FIELD - 1 - fi) { rem -= FIELD - 1 - fi; ++fi; }
    const int fj = fi + 1 + rem;

    const int tid = threadIdx.x;
    const int wv  = tid >> 6;        // wave 0..3
    const int l   = tid & 63;        // lane
    const int lr  = l & 15;          // row-in-16-tile
    const int g   = l >> 4;          // k-group 0..3
    const int bw  = b0 + wv * 64;    // this wave's 64 batch rows

    // "A" operand = W (rows = e): lane holds W[p][n*16+lr][g*8 .. g*8+7]
    bf16x8 wfrag[2];
    #pragma unroll
    for (int n = 0; n < 2; ++n) {
        const float* wp = W + ((size_t)p * EDIM + n * 16 + lr) * EDIM + g * 8;
        const float4 w0 = *(const float4*)wp;
        const float4 w1 = *(const float4*)(wp + 4);
        wfrag[n] = cvt8(w0, w1);
    }

    // "B" operand = xi^T (cols = b): lane holds x[bw+t*16+lr][fi][g*8 .. +7]
    bf16x8 xfrag[4];
    #pragma unroll
    for (int t = 0; t < 4; ++t) {
        const int b = bw + t * 16 + lr;
        const float* xp = x + ((size_t)b * FIELD + fi) * EDIM + g * 8;
        const float4 a0 = *(const float4*)xp;
        const float4 a1 = *(const float4*)(xp + 4);
        xfrag[t] = cvt8(a0, a1);
    }

    // D[e][b] tiles: acc[t][n], lane -> (e = n*16 + g*4 + reg, b = bw + t*16 + lr)
    f32x4 acc[4][2];
    #pragma unroll
    for (int t = 0; t < 4; ++t)
        #pragma unroll
        for (int n = 0; n < 2; ++n)
            acc[t][n] = __builtin_amdgcn_mfma_f32_16x16x32_bf16(
                wfrag[n], xfrag[t], (f32x4){0.f, 0.f, 0.f, 0.f}, 0, 0, 0);

    // Epilogue: r = (t + bias[p][e]) * x[b][fj][e]; float4 stores (4 consecutive e).
    const int e0g = g * 4;
    float4 bias4[2];
    #pragma unroll
    for (int n = 0; n < 2; ++n)
        bias4[n] = *(const float4*)(bias + (size_t)p * EDIM + n * 16 + e0g);

    #pragma unroll
    for (int t = 0; t < 4; ++t) {
        const int b = bw + t * 16 + lr;
        #pragma unroll
        for (int n = 0; n < 2; ++n) {
            const int e0 = n * 16 + e0g;
            const float4 xj4 = *(const float4*)(x + ((size_t)b * FIELD + fj) * EDIM + e0);
            float4 r;
            r.x = (acc[t][n][0] + bias4[n].x) * xj4.x;
            r.y = (acc[t][n][1] + bias4[n].y) * xj4.y;
            r.z = (acc[t][n][2] + bias4[n].z) * xj4.z;
            r.w = (acc[t][n][3] + bias4[n].w) * xj4.w;
            *(float4*)(out + ((size_t)b * NPAIR + p) * EDIM + e0) = r;
        }
    }
}

extern "C" void kernel_launch(void* const* d_in, const int* in_sizes, int n_in,
                              void* d_out, int out_size, void* d_ws, size_t ws_size,
                              hipStream_t stream) {
    const float* x    = (const float*)d_in[0];
    const float* W    = (const float*)d_in[1];
    const float* bias = (const float*)d_in[2];
    float* out        = (float*)d_out;

    const int B = in_sizes[0] / (FIELD * EDIM);   // 4096
    dim3 grid(NPAIR, B / BTB);                     // p fastest: x batch-tile stays cache-hot
    bilinear_mfma<<<grid, dim3(256), 0, stream>>>(x, W, bias, out);
}